// Round 1
// baseline (228.520 us; speedup 1.0000x reference)
//
#include <hip/hip_runtime.h>
#include <math.h>

// minGRU bidirectional scan, fused single pass.
// x: [8, 512, 8192] fp32. out: [8, 256, 8192] fp32.
// Forward half: h = ch[0:128], gate = ch[128:256] -> out ch[0:128]
// Backward half: h = ch[256:384], gate = ch[384:512] -> out ch[128:256], scanned reversed.
//
// Recurrence (equivalent to reference log-space form):
//   a_t = sigmoid(-gate_t); b_t = sigmoid(gate_t) * g(h_t); H_t = a_t*H_{t-1} + b_t
//   g(h) = h>=0 ? h+1 : exp(h)

#define SEQ_L 8192
#define NTHREADS 256
#define PER_THREAD 8
#define TILE (NTHREADS * PER_THREAD)   // 2048
#define NTILES (SEQ_L / TILE)          // 4

__global__ __launch_bounds__(NTHREADS) void mingru_scan_kernel(
    const float* __restrict__ x, float* __restrict__ out) {
    const int blk = blockIdx.x;          // 0..2047
    const int dir = blk >> 10;           // 0 = forward, 1 = backward
    const int s   = blk & 1023;          // sequence id within direction
    const int b   = s >> 7;              // batch 0..7
    const int c   = s & 127;             // channel 0..127

    const int tid  = threadIdx.x;
    const int lane = tid & 63;
    const int wave = tid >> 6;

    const float* __restrict__ hrow = x + (size_t)((b * 512) + (dir * 256) + c) * SEQ_L;
    const float* __restrict__ grow = x + (size_t)((b * 512) + (dir * 256) + 128 + c) * SEQ_L;
    float* __restrict__ orow = out + (size_t)((b * 256) + (dir * 128) + c) * SEQ_L;

    __shared__ float sA[4];
    __shared__ float sB[4];

    float carry = 0.0f;   // scan state entering current tile (initial state = 0)

    for (int tile = 0; tile < NTILES; ++tile) {
        const int base = tile * TILE + tid * PER_THREAD; // element index in SCAN order

        // ---- load 8 h and 8 gate values (float4 pairs; reversed for backward) ----
        float hv[PER_THREAD], gv[PER_THREAD];
        if (dir == 0) {
            float4 h0 = *(const float4*)(hrow + base);
            float4 h1 = *(const float4*)(hrow + base + 4);
            float4 g0 = *(const float4*)(grow + base);
            float4 g1 = *(const float4*)(grow + base + 4);
            hv[0]=h0.x; hv[1]=h0.y; hv[2]=h0.z; hv[3]=h0.w;
            hv[4]=h1.x; hv[5]=h1.y; hv[6]=h1.z; hv[7]=h1.w;
            gv[0]=g0.x; gv[1]=g0.y; gv[2]=g0.z; gv[3]=g0.w;
            gv[4]=g1.x; gv[5]=g1.y; gv[6]=g1.z; gv[7]=g1.w;
        } else {
            // scan index t -> physical index SEQ_L-1-t ; 8-run covers p..p+7
            const int p = SEQ_L - base - PER_THREAD;
            float4 h0 = *(const float4*)(hrow + p);      // phys p..p+3
            float4 h1 = *(const float4*)(hrow + p + 4);  // phys p+4..p+7
            float4 g0 = *(const float4*)(grow + p);
            float4 g1 = *(const float4*)(grow + p + 4);
            hv[0]=h1.w; hv[1]=h1.z; hv[2]=h1.y; hv[3]=h1.x;
            hv[4]=h0.w; hv[5]=h0.z; hv[6]=h0.y; hv[7]=h0.x;
            gv[0]=g1.w; gv[1]=g1.z; gv[2]=g1.y; gv[3]=g1.x;
            gv[4]=g0.w; gv[5]=g0.z; gv[6]=g0.y; gv[7]=g0.x;
        }

        // ---- per-element coefficients + local (thread) scan aggregate ----
        float av[PER_THREAD], bv[PER_THREAD];
        float pa = 1.0f, pb = 0.0f;  // thread aggregate transform (a, b)
#pragma unroll
        for (int j = 0; j < PER_THREAD; ++j) {
            const float gt = gv[j];
            const float e  = __expf(-fabsf(gt));
            const float r  = 1.0f / (1.0f + e);
            const float sn = e * r;   // sigmoid(-|gt|)
            const float sp = r;       // sigmoid(+|gt|)
            const float z  = (gt >= 0.0f) ? sp : sn;  // sigmoid(gt)
            const float a  = (gt >= 0.0f) ? sn : sp;  // sigmoid(-gt) = 1-z
            const float hh = hv[j];
            const float gf = (hh >= 0.0f) ? (hh + 1.0f) : __expf(hh);
            const float bb = z * gf;
            av[j] = a; bv[j] = bb;
            pb = a * pb + bb;
            pa = a * pa;
        }

        // ---- inclusive wave scan of (pa,pb) composition: later ∘ earlier ----
#pragma unroll
        for (int d = 1; d < 64; d <<= 1) {
            const float oa = __shfl_up(pa, d);
            const float ob = __shfl_up(pb, d);
            if (lane >= d) {
                pb = pa * ob + pb;   // uses pre-update pa
                pa = pa * oa;
            }
        }

        if (lane == 63) { sA[wave] = pa; sB[wave] = pb; }
        __syncthreads();

        // ---- state entering this thread: carry -> wave-exclusive -> thread-exclusive ----
        float st = carry;
        for (int w = 0; w < wave; ++w) st = sA[w] * st + sB[w];  // wave-uniform loop
        float ea = __shfl_up(pa, 1);
        float eb = __shfl_up(pb, 1);
        if (lane == 0) { ea = 1.0f; eb = 0.0f; }
        st = ea * st + eb;

        // ---- run the 8 elements with true incoming state; collect outputs ----
        float ov[PER_THREAD];
        float H = st;
#pragma unroll
        for (int j = 0; j < PER_THREAD; ++j) {
            H = av[j] * H + bv[j];
            ov[j] = H;
        }

        // ---- store (reversed for backward) ----
        if (dir == 0) {
            *(float4*)(orow + base)     = make_float4(ov[0], ov[1], ov[2], ov[3]);
            *(float4*)(orow + base + 4) = make_float4(ov[4], ov[5], ov[6], ov[7]);
        } else {
            const int p = SEQ_L - base - PER_THREAD;
            *(float4*)(orow + p)     = make_float4(ov[7], ov[6], ov[5], ov[4]);
            *(float4*)(orow + p + 4) = make_float4(ov[3], ov[2], ov[1], ov[0]);
        }

        // ---- fold all 4 wave aggregates into new carry for next tile ----
        float nc = carry;
#pragma unroll
        for (int w = 0; w < 4; ++w) nc = sA[w] * nc + sB[w];
        carry = nc;
        __syncthreads();  // protect sA/sB before next tile overwrites
    }
}

extern "C" void kernel_launch(void* const* d_in, const int* in_sizes, int n_in,
                              void* d_out, int out_size, void* d_ws, size_t ws_size,
                              hipStream_t stream) {
    const float* x = (const float*)d_in[0];
    float* out = (float*)d_out;
    // 2048 blocks = 8 batch * 128 channels * 2 directions
    mingru_scan_kernel<<<2048, NTHREADS, 0, stream>>>(x, out);
}

// Round 2
// 209.630 us; speedup vs baseline: 1.0901x; 1.0901x over previous
//
#include <hip/hip_runtime.h>
#include <math.h>

// minGRU bidirectional scan, fused single pass, software-pipelined.
// x: [8, 512, 8192] fp32. out: [8, 256, 8192] fp32.
//   a_t = sigmoid(-gate_t); b_t = sigmoid(gate_t)*g(h_t); H_t = a_t*H_{t-1} + b_t
//   g(h) = h>=0 ? h+1 : exp(h)
// Per-thread local scan from zero state + prefix products; true output recovered as
//   ov[j] = ov0[j] + st * pp[j]   (st = state entering this thread)

#define SEQ_L 8192
#define NTHREADS 256
#define PER_THREAD 8
#define TILE (NTHREADS * PER_THREAD)   // 2048
#define NTILES (SEQ_L / TILE)          // 4

__global__ __launch_bounds__(NTHREADS) void mingru_scan_kernel(
    const float* __restrict__ x, float* __restrict__ out) {
    const int blk = blockIdx.x;          // 0..2047
    const int dir = blk >> 10;           // 0 = forward, 1 = backward
    const int s   = blk & 1023;
    const int b   = s >> 7;              // batch 0..7
    const int c   = s & 127;             // channel 0..127

    const int tid  = threadIdx.x;
    const int lane = tid & 63;
    const int wave = tid >> 6;

    const float* __restrict__ hrow = x + (size_t)((b * 512) + (dir * 256) + c) * SEQ_L;
    const float* __restrict__ grow = hrow + (size_t)128 * SEQ_L;
    float* __restrict__ orow = out + (size_t)((b * 256) + (dir * 128) + c) * SEQ_L;

    __shared__ float sA[2][4];
    __shared__ float sB[2][4];

    float carry = 0.0f;

    // ---- prefetch tile 0 (raw float4s, physical order) ----
    {
        // nothing
    }
    int base0 = tid * PER_THREAD;
    int idx0  = dir ? (SEQ_L - base0 - PER_THREAD) : base0;
    float4 nh0 = *(const float4*)(hrow + idx0);
    float4 nh1 = *(const float4*)(hrow + idx0 + 4);
    float4 ng0 = *(const float4*)(grow + idx0);
    float4 ng1 = *(const float4*)(grow + idx0 + 4);

#pragma unroll
    for (int t = 0; t < NTILES; ++t) {
        const float4 h0 = nh0, h1 = nh1, g0 = ng0, g1 = ng1;

        // ---- issue next tile's loads BEFORE any compute (overlap latency) ----
        if (t + 1 < NTILES) {
            const int nb = (t + 1) * TILE + tid * PER_THREAD;
            const int ni = dir ? (SEQ_L - nb - PER_THREAD) : nb;
            nh0 = *(const float4*)(hrow + ni);
            nh1 = *(const float4*)(hrow + ni + 4);
            ng0 = *(const float4*)(grow + ni);
            ng1 = *(const float4*)(grow + ni + 4);
        }

        // ---- unpack into scan order (register permutation, block-uniform branch) ----
        float hv[PER_THREAD], gv[PER_THREAD];
        if (dir == 0) {
            hv[0]=h0.x; hv[1]=h0.y; hv[2]=h0.z; hv[3]=h0.w;
            hv[4]=h1.x; hv[5]=h1.y; hv[6]=h1.z; hv[7]=h1.w;
            gv[0]=g0.x; gv[1]=g0.y; gv[2]=g0.z; gv[3]=g0.w;
            gv[4]=g1.x; gv[5]=g1.y; gv[6]=g1.z; gv[7]=g1.w;
        } else {
            hv[0]=h1.w; hv[1]=h1.z; hv[2]=h1.y; hv[3]=h1.x;
            hv[4]=h0.w; hv[5]=h0.z; hv[6]=h0.y; hv[7]=h0.x;
            gv[0]=g1.w; gv[1]=g1.z; gv[2]=g1.y; gv[3]=g1.x;
            gv[4]=g0.w; gv[5]=g0.z; gv[6]=g0.y; gv[7]=g0.x;
        }

        // ---- coefficients + local scan from zero state; keep (ov0, pp) ----
        float pp[PER_THREAD], ov0[PER_THREAD];
        float ca = 1.0f, cb = 0.0f;
#pragma unroll
        for (int j = 0; j < PER_THREAD; ++j) {
            const float gt = gv[j];
            const float e  = __expf(-fabsf(gt));
            const float r  = 1.0f / (1.0f + e);
            const float sn = e * r;                   // sigmoid(-|gt|)
            const float z  = (gt >= 0.0f) ? r  : sn;  // sigmoid(gt)
            const float a  = (gt >= 0.0f) ? sn : r;   // sigmoid(-gt)
            const float hh = hv[j];
            const float gf = (hh >= 0.0f) ? (hh + 1.0f) : __expf(hh);
            const float bb = z * gf;
            cb = a * cb + bb;
            ca = a * ca;
            ov0[j] = cb;
            pp[j]  = ca;
        }

        // ---- inclusive wave scan of (pa,pb) pair composition ----
        float pa = ca, pb = cb;
#pragma unroll
        for (int d = 1; d < 64; d <<= 1) {
            const float oa = __shfl_up(pa, d);
            const float ob = __shfl_up(pb, d);
            if (lane >= d) {
                pb = pa * ob + pb;   // pre-update pa
                pa = pa * oa;
            }
        }

        const int buf = t & 1;
        if (lane == 63) { sA[buf][wave] = pa; sB[buf][wave] = pb; }
        __syncthreads();   // single barrier per tile (double-buffered sA/sB)

        // ---- state entering this thread ----
        float st = carry;
        for (int w = 0; w < wave; ++w) st = sA[buf][w] * st + sB[buf][w];
        float ea = __shfl_up(pa, 1);
        float eb = __shfl_up(pb, 1);
        if (lane == 0) { ea = 1.0f; eb = 0.0f; }
        st = ea * st + eb;

        // ---- outputs via correction (independent fmas, no serial chain) ----
        float ov[PER_THREAD];
#pragma unroll
        for (int j = 0; j < PER_THREAD; ++j) ov[j] = ov0[j] + st * pp[j];

        // ---- store (reversed for backward) ----
        const int base = t * TILE + tid * PER_THREAD;
        if (dir == 0) {
            *(float4*)(orow + base)     = make_float4(ov[0], ov[1], ov[2], ov[3]);
            *(float4*)(orow + base + 4) = make_float4(ov[4], ov[5], ov[6], ov[7]);
        } else {
            const int p = SEQ_L - base - PER_THREAD;
            *(float4*)(orow + p)     = make_float4(ov[7], ov[6], ov[5], ov[4]);
            *(float4*)(orow + p + 4) = make_float4(ov[3], ov[2], ov[1], ov[0]);
        }

        // ---- fold wave aggregates into carry for next tile ----
        float nc = carry;
#pragma unroll
        for (int w = 0; w < 4; ++w) nc = sA[buf][w] * nc + sB[buf][w];
        carry = nc;
        // no trailing barrier: next tile writes the OTHER sA/sB buffer;
        // this buffer is only rewritten at tile t+2, after tile t+1's barrier.
    }
}

extern "C" void kernel_launch(void* const* d_in, const int* in_sizes, int n_in,
                              void* d_out, int out_size, void* d_ws, size_t ws_size,
                              hipStream_t stream) {
    const float* x = (const float*)d_in[0];
    float* out = (float*)d_out;
    mingru_scan_kernel<<<2048, NTHREADS, 0, stream>>>(x, out);
}